// Round 7
// baseline (130.517 us; speedup 1.0000x reference)
//
#include <hip/hip_runtime.h>
#include <hip/hip_bf16.h>
#include <math.h>

#define BS 1024
#define D 128
#define NP 100000
#define PROWS 100096              // padded to multiple of 128 (96 zero rows)
#define CH 128                    // proxies per chunk/block
#define NCH (PROWS / CH)          // 782
#define NSLICE 16                 // rowsum slices (atomic contention / 16)
#define LOG2E 1.44269504088896340736f

typedef float f32x4 __attribute__((ext_vector_type(4)));
typedef float f32x16 __attribute__((ext_vector_type(16)));
typedef __bf16 bf16x8 __attribute__((ext_vector_type(8)));
typedef unsigned short u16x8 __attribute__((ext_vector_type(8)));

#if defined(__has_builtin)
#if __has_builtin(__builtin_amdgcn_exp2f)
#define FAST_EXP2(x) __builtin_amdgcn_exp2f(x)
#endif
#endif
#ifndef FAST_EXP2
#define FAST_EXP2(x) exp2f(x)
#endif

static __device__ __forceinline__ unsigned short f2bf(float x) {
    unsigned int u = __float_as_uint(x);
    return (unsigned short)((u + 0x7fffu + ((u >> 16) & 1u)) >> 16);  // RNE
}

// ---------- kernel 1: batch -> bf16 A (FRAGMENT-READY layout), d_pos ------
// A element (col,k) stored at byte
//   ((col>>5)*8 + (k>>4))*1024 + ((k>>3)&1)*512 + (col&31)*16 + (k&7)*2
// so main_kernel's B-frag load for (col_blk, s) is base + lane*16:
// one fully-coalesced 1KB load per wave instruction (was a 32-line gather).
// Layout validated rounds 3-6 (absmax 0.0). Worth -15% on main (round 5).
__global__ __launch_bounds__(256) void prep_kernel(
    const float* __restrict__ batch, const float* __restrict__ proxies,
    const int* __restrict__ labels, unsigned short* __restrict__ A,
    float* __restrict__ d_pos, float* __restrict__ rowsum,
    float* __restrict__ out)
{
    // zero the 16x1024 rowsum slices (128 blocks x 128 entries)
    if (threadIdx.x < 128) rowsum[blockIdx.x * 128 + threadIdx.x] = 0.f;
    if (blockIdx.x == 0 && threadIdx.x == 0) out[0] = 0.f;

    int wave = threadIdx.x >> 6, lane = threadIdx.x & 63;
    int sub = lane >> 5, c = lane & 31;
    int row = blockIdx.x * 8 + wave * 2 + sub;   // 0..1023  (= batch column)
    float4 v = *(const float4*)(batch + (size_t)row * D + c * 4);
    float ss = v.x*v.x + v.y*v.y + v.z*v.z + v.w*v.w;
    #pragma unroll
    for (int m = 1; m < 32; m <<= 1) ss += __shfl_xor(ss, m, 64);
    float sc = 3.0f / fmaxf(sqrtf(ss), 1e-12f);
    ushort4 pk;
    pk.x = f2bf(v.x*sc); pk.y = f2bf(v.y*sc);
    pk.z = f2bf(v.z*sc); pk.w = f2bf(v.w*sc);
    // k0 = 4c: s = c>>2, hi = (c>>1)&1, j0 = (c&1)*4
    {
        int col_blk = row >> 5, lr = row & 31;
        int s = c >> 2, h2 = (c >> 1) & 1, j0 = (c & 1) * 4;
        size_t off = (((size_t)(col_blk * 8 + s) * 2 + h2) << 9) + lr * 16 + j0 * 2;
        *(ushort4*)((char*)A + off) = pk;
    }
    // d_pos in fp32: 18 - 2*(b.p_label)
    int lab = labels[row];
    float4 p4 = *(const float4*)(proxies + (size_t)lab * D + c * 4);
    float ps = p4.x*p4.x + p4.y*p4.y + p4.z*p4.z + p4.w*p4.w;
    #pragma unroll
    for (int m = 1; m < 32; m <<= 1) ps += __shfl_xor(ps, m, 64);
    float psc = 3.0f / fmaxf(sqrtf(ps), 1e-12f);
    float dt = (v.x*sc)*(p4.x*psc) + (v.y*sc)*(p4.y*psc)
             + (v.z*sc)*(p4.z*psc) + (v.w*sc)*(p4.w*psc);
    #pragma unroll
    for (int m = 1; m < 32; m <<= 1) dt += __shfl_xor(dt, m, 64);
    if (c == 0) d_pos[row] = 18.0f - 2.0f * dt;
}

// ---------- kernel 2: fused proxy-norm + GEMM + exp row-sums --------------
// 256 threads (4 waves). NEW combination (never tried together):
//   * A-operand (all 128 proxies x K=128) cached in 128 regs per wave,
//     filled from XOR-swizzled LDS ONCE (32 ds_read_b128/wave, was 256).
//     LDS-pipe demand drops 8x: 37.5K -> 4.7K cy/CU.
//   * Bf loads coalesced via fragment-ready A layout (round-5 proven).
//   * Inner loop: pure reg-operand MFMA + exp epilogue. No LDS, no gather.
// Two interleaved st-chains (acc0/acc1) halve the serial MFMA dep chain;
// sched_barrier(0) between the two st-pairs stops the compiler fusing all
// 4 chains (64 acc live -> spill). Budget: Af 128 (AGPR-able: gfx950 MFMA
// reads A from AGPR) + Bf 32 + acc 32 + misc ~20 = ~212 < 256-unified cap.
// __launch_bounds__ law (rounds 1/2/4/5): reg cap = 256/arg2. ONLY arg=2
// has ever produced a no-spill compile of this working set. NEVER arg=4.
__global__ __launch_bounds__(256, 2) void main_kernel(
    const float* __restrict__ proxies,
    const unsigned short* __restrict__ Abat,   // fragment-ready layout
    float* __restrict__ rowsum)                // [NSLICE][BS]
{
    __shared__ unsigned short Plds[CH * D];    // 32 KB
    const int tid = threadIdx.x;
    const int lane = tid & 63;
    const int wave = tid >> 6;                 // 0..3
    const int l31 = lane & 31, hi = lane >> 5;
    const int chunk = blockIdx.x;

    // ---- staging: r = tid>>1 (0..127), q = tid&1 (64 floats each) --------
    {
        int r = tid >> 1, q = tid & 1;
        int pidx = chunk * CH + r;
        const float* src = proxies + (size_t)pidx * D + q * 64;
        float ss = 0.f;
        if (pidx < NP) {
            #pragma unroll
            for (int j = 0; j < 16; ++j) {
                float4 v = *(const float4*)(src + j * 4);
                ss += v.x*v.x + v.y*v.y + v.z*v.z + v.w*v.w;
            }
        }
        ss += __shfl_xor(ss, 1, 64);             // combine the 2 halves
        float sc = 3.0f / fmaxf(sqrtf(ss), 1e-12f);
        #pragma unroll
        for (int i2 = 0; i2 < 8; ++i2) {
            u16x8 w = (u16x8){0,0,0,0,0,0,0,0};
            if (pidx < NP) {
                float4 a = *(const float4*)(src + i2 * 8);      // L1/L2 hit
                float4 b = *(const float4*)(src + i2 * 8 + 4);
                w[0] = f2bf(a.x*sc); w[1] = f2bf(a.y*sc);
                w[2] = f2bf(a.z*sc); w[3] = f2bf(a.w*sc);
                w[4] = f2bf(b.x*sc); w[5] = f2bf(b.y*sc);
                w[6] = f2bf(b.z*sc); w[7] = f2bf(b.w*sc);
            }
            int cl = q * 8 + i2;                 // 16B chunk index in row
            *(u16x8*)((char*)Plds + r * 256 + ((cl ^ (r & 15)) << 4)) = w;
        }
    }
    __syncthreads();

    const int rx = l31 & 15;                     // swizzle key for A reads
    // ---- register A-cache: whole 128-proxy chunk, read LDS exactly once --
    // Af[st][s]: proxy row = st*32 + l31, k = s*16 + hi*8 + j. Same swizzled
    // addresses as round 6's inner loop (validated absmax 0.0).
    bf16x8 Af[4][8];
    #pragma unroll
    for (int st = 0; st < 4; ++st) {
        const char* arow = (const char*)Plds + (st * 32 + l31) * 256;
        #pragma unroll
        for (int s = 0; s < 8; ++s)
            Af[st][s] = *(const bf16x8*)(arow + (((s * 2 + hi) ^ rx) << 4));
    }

    const float c1 = 2.0f * LOG2E, c0 = -18.0f * LOG2E;
    float* rs_base = rowsum + (size_t)(chunk & (NSLICE - 1)) * BS;

    #pragma unroll 1
    for (int outer = 0; outer < 8; ++outer) {
        // this wave's 32 batch columns for this pass
        const int col_blk = wave * 8 + outer;    // 0..31
        const int col0 = col_blk * 32;
        // B-frags: 32 cols x K=128 -> 8 x bf16x8 = 32 VGPRs, coalesced 1KB.
        const char* bp = (const char*)Abat + ((size_t)col_blk << 13) + lane * 16;
        bf16x8 Bf[8];
        #pragma unroll
        for (int s = 0; s < 8; ++s)
            Bf[s] = *(const bf16x8*)(bp + ((size_t)s << 10));

        float rs = 0.f;
        // ---- st-pair 0: chains st=0,1 interleaved (2x ILP on MFMA) ------
        {
            f32x16 a0 = {0.f,0.f,0.f,0.f,0.f,0.f,0.f,0.f,
                         0.f,0.f,0.f,0.f,0.f,0.f,0.f,0.f};
            f32x16 a1 = a0;
            #pragma unroll
            for (int s = 0; s < 8; ++s) {
                a0 = __builtin_amdgcn_mfma_f32_32x32x16_bf16(Af[0][s], Bf[s], a0, 0, 0, 0);
                a1 = __builtin_amdgcn_mfma_f32_32x32x16_bf16(Af[1][s], Bf[s], a1, 0, 0, 0);
            }
            float e0 = 0.f, e1 = 0.f, e2 = 0.f, e3 = 0.f;
            #pragma unroll
            for (int r = 0; r < 4; ++r) {
                e0 += FAST_EXP2(fmaf(a0[4*r+0], c1, c0));
                e1 += FAST_EXP2(fmaf(a0[4*r+1], c1, c0));
                e2 += FAST_EXP2(fmaf(a0[4*r+2], c1, c0));
                e3 += FAST_EXP2(fmaf(a0[4*r+3], c1, c0));
                e0 += FAST_EXP2(fmaf(a1[4*r+0], c1, c0));
                e1 += FAST_EXP2(fmaf(a1[4*r+1], c1, c0));
                e2 += FAST_EXP2(fmaf(a1[4*r+2], c1, c0));
                e3 += FAST_EXP2(fmaf(a1[4*r+3], c1, c0));
            }
            rs += (e0 + e1) + (e2 + e3);
        }
        __builtin_amdgcn_sched_barrier(0);   // cap live acc at 32 regs
        // ---- st-pair 1: chains st=2,3 ----------------------------------
        {
            f32x16 a0 = {0.f,0.f,0.f,0.f,0.f,0.f,0.f,0.f,
                         0.f,0.f,0.f,0.f,0.f,0.f,0.f,0.f};
            f32x16 a1 = a0;
            #pragma unroll
            for (int s = 0; s < 8; ++s) {
                a0 = __builtin_amdgcn_mfma_f32_32x32x16_bf16(Af[2][s], Bf[s], a0, 0, 0, 0);
                a1 = __builtin_amdgcn_mfma_f32_32x32x16_bf16(Af[3][s], Bf[s], a1, 0, 0, 0);
            }
            float e0 = 0.f, e1 = 0.f, e2 = 0.f, e3 = 0.f;
            #pragma unroll
            for (int r = 0; r < 4; ++r) {
                e0 += FAST_EXP2(fmaf(a0[4*r+0], c1, c0));
                e1 += FAST_EXP2(fmaf(a0[4*r+1], c1, c0));
                e2 += FAST_EXP2(fmaf(a0[4*r+2], c1, c0));
                e3 += FAST_EXP2(fmaf(a0[4*r+3], c1, c0));
                e0 += FAST_EXP2(fmaf(a1[4*r+0], c1, c0));
                e1 += FAST_EXP2(fmaf(a1[4*r+1], c1, c0));
                e2 += FAST_EXP2(fmaf(a1[4*r+2], c1, c0));
                e3 += FAST_EXP2(fmaf(a1[4*r+3], c1, c0));
            }
            rs += (e0 + e1) + (e2 + e3);
        }
        rs += __shfl_xor(rs, 32, 64);            // combine the two row-halves
        if (hi == 0)
            atomicAdd(rs_base + col0 + l31, rs);
    }
}

// ---------- kernel 3: final lse + mean (4 blocks, atomicAdd out) ----------
__global__ __launch_bounds__(256) void final_kernel(
    const float* __restrict__ rowsum, const float* __restrict__ d_pos,
    float* __restrict__ out)
{
    int row = blockIdx.x * 256 + threadIdx.x;
    float tot = 0.f;
    #pragma unroll
    for (int s = 0; s < NSLICE; ++s)
        tot += rowsum[(size_t)s * BS + row];
    float dp = d_pos[row];
    const float PADC = 96.0f * exp2f(-18.0f * LOG2E);  // zero-pad rows
    float neg = tot - expf(-dp) - PADC;                // drop own column
    float val = dp + logf(fmaxf(neg, 1e-37f));
    #pragma unroll
    for (int m = 1; m < 64; m <<= 1) val += __shfl_xor(val, m, 64);
    __shared__ float red[4];
    if ((threadIdx.x & 63) == 0) red[threadIdx.x >> 6] = val;
    __syncthreads();
    if (threadIdx.x == 0) {
        float v = (red[0] + red[1]) + (red[2] + red[3]);
        atomicAdd(out, v * (1.0f / 1024.0f));
    }
}

extern "C" void kernel_launch(void* const* d_in, const int* in_sizes, int n_in,
                              void* d_out, int out_size, void* d_ws, size_t ws_size,
                              hipStream_t stream) {
    const float* batch   = (const float*)d_in[0];
    const float* proxies = (const float*)d_in[1];
    const int*   labels  = (const int*)d_in[2];
    float* out = (float*)d_out;

    char* ws = (char*)d_ws;
    unsigned short* A  = (unsigned short*)ws;                    //   262,144 B
    float* d_pos       = (float*)(ws + 262144);                  //     4,096 B
    float* rowsum      = (float*)(ws + 266240);                  //    65,536 B

    prep_kernel<<<128, 256, 0, stream>>>(batch, proxies, labels, A, d_pos, rowsum, out);
    main_kernel<<<NCH, 256, 0, stream>>>(proxies, A, rowsum);
    final_kernel<<<4, 256, 0, stream>>>(rowsum, d_pos, out);
}